// Round 1
// baseline (106.435 us; speedup 1.0000x reference)
//
#include <hip/hip_runtime.h>
#include <hip/hip_bf16.h>

#define FEAT   256
#define K2     512      // 2*FEAT
#define BATCH  50000
#define NS     10
#define EMBED  256

#define BN 64
#define BK 64

typedef __attribute__((ext_vector_type(8))) __bf16         bf16x8;
typedef __attribute__((ext_vector_type(8))) unsigned short ushort8;
typedef __attribute__((ext_vector_type(4))) unsigned short ushort4v;
typedef __attribute__((ext_vector_type(4))) float          f32x4;

static __device__ __forceinline__ unsigned short f2bf(float x) {
    // round-to-nearest-even f32 -> bf16 (inputs are finite)
    unsigned int u = __builtin_bit_cast(unsigned int, x);
    u += 0x7FFFu + ((u >> 16) & 1u);
    return (unsigned short)(u >> 16);
}

// ---- one-time weight f32 -> bf16 conversion into workspace (256 KB) ----
__global__ void wconv_kernel(const float* __restrict__ w,
                             unsigned short* __restrict__ wb) {
    int i = blockIdx.x * blockDim.x + threadIdx.x;   // 32768 threads, 4 elems each
    f32x4 v = ((const f32x4*)w)[i];
    ushort4v h;
    h[0] = f2bf(v[0]); h[1] = f2bf(v[1]); h[2] = f2bf(v[2]); h[3] = f2bf(v[3]);
    ((ushort4v*)wb)[i] = h;
}

// ---- fused gather/mean/concat + bf16 MFMA GEMM + relu ----
// out[m][n] = relu( sum_k W[m][k] * combined[n][k] ),  m<256, n<50000, k<512
// combined[n][k] = k<256 ? F[nodes[n]][k] : mean_s F[neigh[n][s]][k-256]
__global__ void gemm_fused(const float* __restrict__ features,
                           const unsigned short* __restrict__ wb,
                           const int* __restrict__ nodes,
                           const int* __restrict__ neigh,
                           float* __restrict__ out) {
    __shared__ __align__(16) unsigned short lA[EMBED * BK]; // 32 KB
    __shared__ __align__(16) unsigned short lB[BN * BK];    //  8 KB

    const int tid  = threadIdx.x;
    const int nb0  = blockIdx.x * BN;
    const int w    = tid >> 6;       // wave 0..3 -> m rows [w*64, w*64+64)
    const int lane = tid & 63;
    const int lr   = lane & 15;
    const int lg   = lane >> 4;

    f32x4 acc[4][4] = {};

    for (int kt = 0; kt < K2 / BK; ++kt) {
        const int k0 = kt * BK;
        __syncthreads();

        // ---- stage A: weight[0:256][k0:k0+64] bf16 -> lA (swizzled) ----
        #pragma unroll
        for (int i = 0; i < 8; ++i) {
            int a   = i * 256 + tid;
            int row = a >> 3;
            int ch  = a & 7;
            ushort8 v = *(const ushort8*)(wb + row * K2 + k0 + ch * 8);
            *(ushort8*)&lA[row * BK + ((ch ^ (row & 7)) << 3)] = v;
        }

        // ---- stage B: combined[nb0:nb0+64][k0:k0+64] -> bf16 lB (swizzled) ----
        #pragma unroll
        for (int i = 0; i < 2; ++i) {
            int a  = i * 256 + tid;
            int r  = a >> 3;
            int ch = a & 7;
            int n  = nb0 + r;
            f32x4 s0 = {0.f, 0.f, 0.f, 0.f};
            f32x4 s1 = {0.f, 0.f, 0.f, 0.f};
            if (n < BATCH) {
                if (kt < 4) {
                    int idx = nodes[n];
                    const f32x4* src = (const f32x4*)(features + idx * FEAT + k0 + ch * 8);
                    s0 = src[0];
                    s1 = src[1];
                } else {
                    const int koff = k0 - FEAT + ch * 8;
                    #pragma unroll
                    for (int s = 0; s < NS; ++s) {
                        int idx = neigh[n * NS + s];
                        const f32x4* src = (const f32x4*)(features + idx * FEAT + koff);
                        s0 += src[0];
                        s1 += src[1];
                    }
                    s0 *= 0.1f;
                    s1 *= 0.1f;
                }
            }
            ushort8 h;
            h[0] = f2bf(s0[0]); h[1] = f2bf(s0[1]); h[2] = f2bf(s0[2]); h[3] = f2bf(s0[3]);
            h[4] = f2bf(s1[0]); h[5] = f2bf(s1[1]); h[6] = f2bf(s1[2]); h[7] = f2bf(s1[3]);
            *(ushort8*)&lB[r * BK + ((ch ^ (r & 7)) << 3)] = h;
        }
        __syncthreads();

        // ---- MFMA: 2 k-steps of 32 ----
        #pragma unroll
        for (int ks = 0; ks < 2; ++ks) {
            const int cf = ks * 4 + lg;   // 8-elem chunk index within 64-col row
            bf16x8 af[4], bfr[4];
            #pragma unroll
            for (int i = 0; i < 4; ++i) {
                int row = (w << 6) + (i << 4) + lr;
                af[i] = *(const bf16x8*)&lA[row * BK + ((cf ^ (row & 7)) << 3)];
            }
            #pragma unroll
            for (int j = 0; j < 4; ++j) {
                int rb = (j << 4) + lr;
                bfr[j] = *(const bf16x8*)&lB[rb * BK + ((cf ^ (rb & 7)) << 3)];
            }
            #pragma unroll
            for (int i = 0; i < 4; ++i)
                #pragma unroll
                for (int j = 0; j < 4; ++j)
                    acc[i][j] = __builtin_amdgcn_mfma_f32_16x16x32_bf16(
                        af[i], bfr[j], acc[i][j], 0, 0, 0);
        }
    }

    // ---- epilogue: relu + store (C/D layout: col=lane&15, row=(lane>>4)*4+reg) ----
    #pragma unroll
    for (int i = 0; i < 4; ++i) {
        int m0 = (w << 6) + (i << 4) + (lg << 2);
        #pragma unroll
        for (int j = 0; j < 4; ++j) {
            int n = nb0 + (j << 4) + lr;
            if (n < BATCH) {
                #pragma unroll
                for (int r = 0; r < 4; ++r) {
                    float v = acc[i][j][r];
                    out[(m0 + r) * BATCH + n] = v > 0.f ? v : 0.f;
                }
            }
        }
    }
}

extern "C" void kernel_launch(void* const* d_in, const int* in_sizes, int n_in,
                              void* d_out, int out_size, void* d_ws, size_t ws_size,
                              hipStream_t stream) {
    const float* features = (const float*)d_in[0];
    const float* weight   = (const float*)d_in[1];
    const int*   nodes    = (const int*)d_in[2];
    const int*   neigh    = (const int*)d_in[3];
    float* out = (float*)d_out;
    unsigned short* wb = (unsigned short*)d_ws;   // 256*512 bf16 = 256 KB

    wconv_kernel<<<(EMBED * K2 / 4) / 256, 256, 0, stream>>>(weight, wb);
    gemm_fused<<<(BATCH + BN - 1) / BN, 256, 0, stream>>>(features, wb, nodes, neigh, out);
}